// Round 1
// baseline (2951.324 us; speedup 1.0000x reference)
//
#include <hip/hip_runtime.h>

#define N_NODES 100000
#define N_EDGES 1600000
#define D 128

// Phase 1: z[dst] += w * x[src]  (z lives in d_out, pre-zeroed); deg[dst] += 1.
// 32 lanes per edge, one float4 per lane.
__global__ __launch_bounds__(256) void scatter_kernel(
    const float* __restrict__ x,
    const int* __restrict__ ei,
    const float* __restrict__ ew,
    float* __restrict__ z,
    float* __restrict__ deg) {
  long long g = (long long)blockIdx.x * 256 + threadIdx.x;
  int e = (int)(g >> 5);
  int lane = (int)(g & 31);
  if (e >= N_EDGES) return;
  int dst = ei[e];             // row = destination (segment id)
  int src = ei[N_EDGES + e];   // col = source (gathered)
  float w = ew[e];
  float4 xv = *reinterpret_cast<const float4*>(x + (size_t)src * D + (lane << 2));
  float* o = z + (size_t)dst * D + (lane << 2);
  atomicAdd(o + 0, w * xv.x);
  atomicAdd(o + 1, w * xv.y);
  atomicAdd(o + 2, w * xv.z);
  atomicAdd(o + 3, w * xv.w);
  if (lane == 0) atomicAdd(deg + dst, 1.0f);
}

// Phase 2: out[r] = x[r]@W_lin + b_lin + z[r]@W_agg + deg[r]*b_agg
// z is read from `out` itself (scatter result); each block owns its 32 rows,
// all global reads of those rows complete before the epilogue write.
__global__ __launch_bounds__(256) void fused_gemm_kernel(
    const float* __restrict__ x,
    const float* __restrict__ Wl,
    const float* __restrict__ bl,
    const float* __restrict__ Wa,
    const float* __restrict__ ba,
    const float* __restrict__ deg,
    float* __restrict__ out) {
  __shared__ float xs[32 * 16];
  __shared__ float zs[32 * 16];
  __shared__ float wls[16 * 128];
  __shared__ float was[16 * 128];
  const int tid = threadIdx.x;
  const int row0 = blockIdx.x * 32;
  const int c4 = tid & 31;   // which float4 column group (0..31)
  const int r0 = tid >> 5;   // 0..7; thread handles rows r0, r0+8, r0+16, r0+24
  float4 acc[4];
#pragma unroll
  for (int i = 0; i < 4; i++) acc[i] = make_float4(0.f, 0.f, 0.f, 0.f);

  for (int k0 = 0; k0 < D; k0 += 16) {
    // stage x tile (waves 0-1) and z tile (waves 2-3): 32 rows x 16 k, float4 each
    {
      int t = tid & 127;
      int r = t >> 2;
      int kc = (t & 3) << 2;
      const float* sp = (tid < 128) ? x : out;
      float* dp = (tid < 128) ? xs : zs;
      *reinterpret_cast<float4*>(dp + r * 16 + kc) =
          *reinterpret_cast<const float4*>(sp + (size_t)(row0 + r) * D + k0 + kc);
    }
    // stage both W tiles: 16 x 128 each, linear float4, conflict-free
#pragma unroll
    for (int i = 0; i < 2; i++) {
      int f = tid + i * 256;
      int kk = f >> 5;
      int cc = (f & 31) << 2;
      *reinterpret_cast<float4*>(wls + kk * 128 + cc) =
          *reinterpret_cast<const float4*>(Wl + (size_t)(k0 + kk) * D + cc);
      *reinterpret_cast<float4*>(was + kk * 128 + cc) =
          *reinterpret_cast<const float4*>(Wa + (size_t)(k0 + kk) * D + cc);
    }
    __syncthreads();
#pragma unroll
    for (int kk = 0; kk < 16; kk++) {
      float4 wl = *reinterpret_cast<const float4*>(wls + kk * 128 + (c4 << 2));
      float4 wa = *reinterpret_cast<const float4*>(was + kk * 128 + (c4 << 2));
#pragma unroll
      for (int rr = 0; rr < 4; rr++) {
        int r2 = r0 + rr * 8;
        float xv = xs[r2 * 16 + kk];
        float zv = zs[r2 * 16 + kk];
        acc[rr].x = fmaf(xv, wl.x, fmaf(zv, wa.x, acc[rr].x));
        acc[rr].y = fmaf(xv, wl.y, fmaf(zv, wa.y, acc[rr].y));
        acc[rr].z = fmaf(xv, wl.z, fmaf(zv, wa.z, acc[rr].z));
        acc[rr].w = fmaf(xv, wl.w, fmaf(zv, wa.w, acc[rr].w));
      }
    }
    __syncthreads();
  }

  float4 blv = *reinterpret_cast<const float4*>(bl + (c4 << 2));
  float4 bav = *reinterpret_cast<const float4*>(ba + (c4 << 2));
#pragma unroll
  for (int rr = 0; rr < 4; rr++) {
    int r = row0 + r0 + rr * 8;
    float d = deg[r];
    float4 o;
    o.x = acc[rr].x + blv.x + d * bav.x;
    o.y = acc[rr].y + blv.y + d * bav.y;
    o.z = acc[rr].z + blv.z + d * bav.z;
    o.w = acc[rr].w + blv.w + d * bav.w;
    *reinterpret_cast<float4*>(out + (size_t)r * D + (c4 << 2)) = o;
  }
}

extern "C" void kernel_launch(void* const* d_in, const int* in_sizes, int n_in,
                              void* d_out, int out_size, void* d_ws, size_t ws_size,
                              hipStream_t stream) {
  const float* x  = (const float*)d_in[0];
  const int*   ei = (const int*)d_in[1];
  const float* ew = (const float*)d_in[2];
  const float* Wl = (const float*)d_in[3];
  const float* bl = (const float*)d_in[4];
  const float* Wa = (const float*)d_in[5];
  const float* ba = (const float*)d_in[6];
  float* out = (float*)d_out;
  float* deg = (float*)d_ws;  // N_NODES floats = 400 KB

  hipMemsetAsync(out, 0, (size_t)N_NODES * D * sizeof(float), stream);
  hipMemsetAsync(deg, 0, (size_t)N_NODES * sizeof(float), stream);

  // 32 lanes per edge -> E*32 threads
  scatter_kernel<<<(N_EDGES * 32) / 256, 256, 0, stream>>>(x, ei, ew, out, deg);
  fused_gemm_kernel<<<N_NODES / 32, 256, 0, stream>>>(x, Wl, bl, Wa, ba, deg, out);
}

// Round 2
// 486.502 us; speedup vs baseline: 6.0664x; 6.0664x over previous
//
#include <hip/hip_runtime.h>

#define N_NODES 100000
#define N_EDGES 1600000
#define D 128
#define SCAN_CHUNK 1024
#define NB_SCAN ((N_NODES + SCAN_CHUNK - 1) / SCAN_CHUNK)  // 98

// ---- workspace layout (ints) ----
// cnt  : [0, 100000)              histogram / fill-cursor / float-deg (aliased)
// off  : [100000, 200001)         CSR offsets
// bsum : [200004, 200132)         per-block sums for scan
// ssrc : [200192, 1800192)        edge sources sorted by dst
// sw   : [1800192, 3400192)       edge weights sorted by dst (float alias)
#define WS_OFF_OFF   100000
#define WS_BSUM_OFF  200004
#define WS_SSRC_OFF  200192
#define WS_SW_OFF    1800192
#define WS_NEEDED_BYTES ((size_t)3400192 * 4)

// ================= CSR-build path =================

__global__ __launch_bounds__(256) void hist_kernel(const int* __restrict__ ei,
                                                   int* __restrict__ cnt) {
  int e = blockIdx.x * 256 + threadIdx.x;
  if (e < N_EDGES) atomicAdd(&cnt[ei[e]], 1);
}

__global__ __launch_bounds__(256) void block_sum_kernel(const int* __restrict__ cnt,
                                                        int* __restrict__ bsum) {
  int base = blockIdx.x * SCAN_CHUNK;
  int s = 0;
#pragma unroll
  for (int k = 0; k < 4; k++) {
    int i = base + (int)threadIdx.x + k * 256;
    if (i < N_NODES) s += cnt[i];
  }
  __shared__ int red[4];
  for (int o = 32; o > 0; o >>= 1) s += __shfl_down(s, o, 64);
  if ((threadIdx.x & 63) == 0) red[threadIdx.x >> 6] = s;
  __syncthreads();
  if (threadIdx.x == 0) bsum[blockIdx.x] = red[0] + red[1] + red[2] + red[3];
}

__global__ __launch_bounds__(128) void scan_bsum_kernel(int* __restrict__ bsum,
                                                        int* __restrict__ off) {
  __shared__ int sh[128];
  int t = threadIdx.x;
  int v = (t < NB_SCAN) ? bsum[t] : 0;
  sh[t] = v;
  __syncthreads();
  for (int o = 1; o < 128; o <<= 1) {
    int add = (t >= o) ? sh[t - o] : 0;
    __syncthreads();
    sh[t] += add;
    __syncthreads();
  }
  if (t < NB_SCAN) bsum[t] = sh[t] - v;   // exclusive block prefix
  if (t == 0) off[N_NODES] = sh[127];     // total = N_EDGES
}

__global__ __launch_bounds__(256) void scan_offsets_kernel(const int* __restrict__ cnt,
                                                           const int* __restrict__ bsum,
                                                           int* __restrict__ off) {
  __shared__ int sh[256];
  int t = threadIdx.x;
  int i0 = blockIdx.x * SCAN_CHUNK + t * 4;
  int c[4];
#pragma unroll
  for (int k = 0; k < 4; k++) c[k] = (i0 + k < N_NODES) ? cnt[i0 + k] : 0;
  int ls = c[0] + c[1] + c[2] + c[3];
  sh[t] = ls;
  __syncthreads();
  for (int o = 1; o < 256; o <<= 1) {
    int add = (t >= o) ? sh[t - o] : 0;
    __syncthreads();
    sh[t] += add;
    __syncthreads();
  }
  int run = bsum[blockIdx.x] + sh[t] - ls;  // exclusive prefix for this thread
#pragma unroll
  for (int k = 0; k < 4; k++) {
    if (i0 + k < N_NODES) off[i0 + k] = run;
    run += c[k];
  }
}

__global__ __launch_bounds__(256) void fill_kernel(const int* __restrict__ ei,
                                                   const float* __restrict__ ew,
                                                   const int* __restrict__ off,
                                                   int* __restrict__ cur,
                                                   int* __restrict__ ssrc,
                                                   float* __restrict__ sw) {
  int e = blockIdx.x * 256 + threadIdx.x;
  if (e >= N_EDGES) return;
  int dst = ei[e];
  int p = off[dst] + atomicAdd(&cur[dst], 1);
  ssrc[p] = ei[N_EDGES + e];
  sw[p] = ew[e];
}

// one half-wave (32 lanes x float4) per node; conflict-free accumulate in regs
__global__ __launch_bounds__(256) void gather_kernel(const float* __restrict__ x,
                                                     const int* __restrict__ off,
                                                     const int* __restrict__ ssrc,
                                                     const float* __restrict__ sw,
                                                     float* __restrict__ z,
                                                     float* __restrict__ degf) {
  int gid = blockIdx.x * 256 + threadIdx.x;
  int n = gid >> 5;
  int lane = gid & 31;
  if (n >= N_NODES) return;
  int beg = off[n], end = off[n + 1];
  float4 acc = make_float4(0.f, 0.f, 0.f, 0.f);
  int s_nxt = 0; float w_nxt = 0.f;
  if (beg < end) { s_nxt = ssrc[beg]; w_nxt = sw[beg]; }
  for (int e = beg; e < end; e++) {
    int s_cur = s_nxt; float w_cur = w_nxt;
    if (e + 1 < end) { s_nxt = ssrc[e + 1]; w_nxt = sw[e + 1]; }
    float4 xv = *reinterpret_cast<const float4*>(x + (size_t)s_cur * D + (lane << 2));
    acc.x = fmaf(w_cur, xv.x, acc.x);
    acc.y = fmaf(w_cur, xv.y, acc.y);
    acc.z = fmaf(w_cur, xv.z, acc.z);
    acc.w = fmaf(w_cur, xv.w, acc.w);
  }
  *reinterpret_cast<float4*>(z + (size_t)n * D + (lane << 2)) = acc;
  if (lane == 0) degf[n] = (float)(end - beg);
}

// ================= fallback atomic path (small ws) =================

__global__ __launch_bounds__(256) void scatter_kernel(const float* __restrict__ x,
                                                      const int* __restrict__ ei,
                                                      const float* __restrict__ ew,
                                                      float* __restrict__ z,
                                                      float* __restrict__ deg) {
  long long g = (long long)blockIdx.x * 256 + threadIdx.x;
  int e = (int)(g >> 5);
  int lane = (int)(g & 31);
  if (e >= N_EDGES) return;
  int dst = ei[e];
  int src = ei[N_EDGES + e];
  float w = ew[e];
  float4 xv = *reinterpret_cast<const float4*>(x + (size_t)src * D + (lane << 2));
  float* o = z + (size_t)dst * D + (lane << 2);
  atomicAdd(o + 0, w * xv.x);
  atomicAdd(o + 1, w * xv.y);
  atomicAdd(o + 2, w * xv.z);
  atomicAdd(o + 3, w * xv.w);
  if (lane == 0) atomicAdd(deg + dst, 1.0f);
}

// ================= fused double-GEMM =================
// out[r] = x[r]@W_lin + b_lin + z[r]@W_agg + deg[r]*b_agg ; z read from `out`

__global__ __launch_bounds__(256) void fused_gemm_kernel(const float* __restrict__ x,
                                                         const float* __restrict__ Wl,
                                                         const float* __restrict__ bl,
                                                         const float* __restrict__ Wa,
                                                         const float* __restrict__ ba,
                                                         const float* __restrict__ deg,
                                                         float* __restrict__ out) {
  __shared__ float xs[32 * 16];
  __shared__ float zs[32 * 16];
  __shared__ float wls[16 * 128];
  __shared__ float was[16 * 128];
  const int tid = threadIdx.x;
  const int row0 = blockIdx.x * 32;
  const int c4 = tid & 31;
  const int r0 = tid >> 5;
  float4 acc[4];
#pragma unroll
  for (int i = 0; i < 4; i++) acc[i] = make_float4(0.f, 0.f, 0.f, 0.f);

  for (int k0 = 0; k0 < D; k0 += 16) {
    {
      int t = tid & 127;
      int r = t >> 2;
      int kc = (t & 3) << 2;
      const float* sp = (tid < 128) ? x : out;
      float* dp = (tid < 128) ? xs : zs;
      *reinterpret_cast<float4*>(dp + r * 16 + kc) =
          *reinterpret_cast<const float4*>(sp + (size_t)(row0 + r) * D + k0 + kc);
    }
#pragma unroll
    for (int i = 0; i < 2; i++) {
      int f = tid + i * 256;
      int kk = f >> 5;
      int cc = (f & 31) << 2;
      *reinterpret_cast<float4*>(wls + kk * 128 + cc) =
          *reinterpret_cast<const float4*>(Wl + (size_t)(k0 + kk) * D + cc);
      *reinterpret_cast<float4*>(was + kk * 128 + cc) =
          *reinterpret_cast<const float4*>(Wa + (size_t)(k0 + kk) * D + cc);
    }
    __syncthreads();
#pragma unroll
    for (int kk = 0; kk < 16; kk++) {
      float4 wl = *reinterpret_cast<const float4*>(wls + kk * 128 + (c4 << 2));
      float4 wa = *reinterpret_cast<const float4*>(was + kk * 128 + (c4 << 2));
#pragma unroll
      for (int rr = 0; rr < 4; rr++) {
        int r2 = r0 + rr * 8;
        float xv = xs[r2 * 16 + kk];
        float zv = zs[r2 * 16 + kk];
        acc[rr].x = fmaf(xv, wl.x, fmaf(zv, wa.x, acc[rr].x));
        acc[rr].y = fmaf(xv, wl.y, fmaf(zv, wa.y, acc[rr].y));
        acc[rr].z = fmaf(xv, wl.z, fmaf(zv, wa.z, acc[rr].z));
        acc[rr].w = fmaf(xv, wl.w, fmaf(zv, wa.w, acc[rr].w));
      }
    }
    __syncthreads();
  }

  float4 blv = *reinterpret_cast<const float4*>(bl + (c4 << 2));
  float4 bav = *reinterpret_cast<const float4*>(ba + (c4 << 2));
#pragma unroll
  for (int rr = 0; rr < 4; rr++) {
    int r = row0 + r0 + rr * 8;
    float d = deg[r];
    float4 o;
    o.x = acc[rr].x + blv.x + d * bav.x;
    o.y = acc[rr].y + blv.y + d * bav.y;
    o.z = acc[rr].z + blv.z + d * bav.z;
    o.w = acc[rr].w + blv.w + d * bav.w;
    *reinterpret_cast<float4*>(out + (size_t)r * D + (c4 << 2)) = o;
  }
}

extern "C" void kernel_launch(void* const* d_in, const int* in_sizes, int n_in,
                              void* d_out, int out_size, void* d_ws, size_t ws_size,
                              hipStream_t stream) {
  const float* x  = (const float*)d_in[0];
  const int*   ei = (const int*)d_in[1];
  const float* ew = (const float*)d_in[2];
  const float* Wl = (const float*)d_in[3];
  const float* bl = (const float*)d_in[4];
  const float* Wa = (const float*)d_in[5];
  const float* ba = (const float*)d_in[6];
  float* out = (float*)d_out;

  if (ws_size >= WS_NEEDED_BYTES) {
    int*   cnt  = (int*)d_ws;
    int*   off  = cnt + WS_OFF_OFF;
    int*   bsum = cnt + WS_BSUM_OFF;
    int*   ssrc = cnt + WS_SSRC_OFF;
    float* sw   = (float*)(cnt + WS_SW_OFF);
    float* degf = (float*)cnt;  // aliased: written by gather after cnt is dead

    hipMemsetAsync(cnt, 0, (size_t)N_NODES * sizeof(int), stream);
    hist_kernel<<<(N_EDGES + 255) / 256, 256, 0, stream>>>(ei, cnt);
    block_sum_kernel<<<NB_SCAN, 256, 0, stream>>>(cnt, bsum);
    scan_bsum_kernel<<<1, 128, 0, stream>>>(bsum, off);
    scan_offsets_kernel<<<NB_SCAN, 256, 0, stream>>>(cnt, bsum, off);
    hipMemsetAsync(cnt, 0, (size_t)N_NODES * sizeof(int), stream);  // cursor
    fill_kernel<<<(N_EDGES + 255) / 256, 256, 0, stream>>>(ei, ew, off, cnt, ssrc, sw);
    gather_kernel<<<(N_NODES * 32 + 255) / 256, 256, 0, stream>>>(x, off, ssrc, sw, out, degf);
    fused_gemm_kernel<<<N_NODES / 32, 256, 0, stream>>>(x, Wl, bl, Wa, ba, degf, out);
  } else {
    float* deg = (float*)d_ws;
    hipMemsetAsync(out, 0, (size_t)N_NODES * D * sizeof(float), stream);
    hipMemsetAsync(deg, 0, (size_t)N_NODES * sizeof(float), stream);
    scatter_kernel<<<(N_EDGES * 32) / 256, 256, 0, stream>>>(x, ei, ew, out, deg);
    fused_gemm_kernel<<<N_NODES / 32, 256, 0, stream>>>(x, Wl, bl, Wa, ba, deg, out);
  }
}

// Round 3
// 455.594 us; speedup vs baseline: 6.4780x; 1.0678x over previous
//
#include <hip/hip_runtime.h>

#define N_NODES 100000
#define N_EDGES 1600000
#define D 128
#define SCAN_CHUNK 1024
#define NB_SCAN ((N_NODES + SCAN_CHUNK - 1) / SCAN_CHUNK)  // 98

// ---- workspace layout (int units) ----
// cnt  : [0, 100000)          histogram / fill-cursor / float-deg (aliased)
// off  : [100000, 200001)     CSR offsets
// bsum : [200004, 200132)     per-block sums for scan
// srt  : [200192, 3400192)    int2 {src, w_bits} sorted by dst (byte off 800768, 8B-aligned)
// xh   : [3400192, 9800192)   x in bf16 (12.8M ushorts, packed as uints)
#define WS_OFF   100000
#define WS_BSUM  200004
#define WS_SRT   200192
#define WS_XH    3400192
#define WS_T1_BYTES ((size_t)3400192 * 4)               // CSR fp32 path
#define WS_T2_BYTES ((size_t)(3400192 + 6400000) * 4)   // + bf16 x copy

// ================= CSR build =================

__global__ __launch_bounds__(256) void hist_kernel(const int* __restrict__ ei,
                                                   int* __restrict__ cnt) {
  int e = blockIdx.x * 256 + threadIdx.x;
  if (e < N_EDGES) atomicAdd(&cnt[ei[e]], 1);
}

__global__ __launch_bounds__(256) void block_sum_kernel(const int* __restrict__ cnt,
                                                        int* __restrict__ bsum) {
  int base = blockIdx.x * SCAN_CHUNK;
  int s = 0;
#pragma unroll
  for (int k = 0; k < 4; k++) {
    int i = base + (int)threadIdx.x + k * 256;
    if (i < N_NODES) s += cnt[i];
  }
  __shared__ int red[4];
  for (int o = 32; o > 0; o >>= 1) s += __shfl_down(s, o, 64);
  if ((threadIdx.x & 63) == 0) red[threadIdx.x >> 6] = s;
  __syncthreads();
  if (threadIdx.x == 0) bsum[blockIdx.x] = red[0] + red[1] + red[2] + red[3];
}

__global__ __launch_bounds__(128) void scan_bsum_kernel(int* __restrict__ bsum,
                                                        int* __restrict__ off) {
  __shared__ int sh[128];
  int t = threadIdx.x;
  int v = (t < NB_SCAN) ? bsum[t] : 0;
  sh[t] = v;
  __syncthreads();
  for (int o = 1; o < 128; o <<= 1) {
    int add = (t >= o) ? sh[t - o] : 0;
    __syncthreads();
    sh[t] += add;
    __syncthreads();
  }
  if (t < NB_SCAN) bsum[t] = sh[t] - v;
  if (t == 0) off[N_NODES] = sh[127];
}

__global__ __launch_bounds__(256) void scan_offsets_kernel(const int* __restrict__ cnt,
                                                           const int* __restrict__ bsum,
                                                           int* __restrict__ off) {
  __shared__ int sh[256];
  int t = threadIdx.x;
  int i0 = blockIdx.x * SCAN_CHUNK + t * 4;
  int c[4];
#pragma unroll
  for (int k = 0; k < 4; k++) c[k] = (i0 + k < N_NODES) ? cnt[i0 + k] : 0;
  int ls = c[0] + c[1] + c[2] + c[3];
  sh[t] = ls;
  __syncthreads();
  for (int o = 1; o < 256; o <<= 1) {
    int add = (t >= o) ? sh[t - o] : 0;
    __syncthreads();
    sh[t] += add;
    __syncthreads();
  }
  int run = bsum[blockIdx.x] + sh[t] - ls;
#pragma unroll
  for (int k = 0; k < 4; k++) {
    if (i0 + k < N_NODES) off[i0 + k] = run;
    run += c[k];
  }
}

// single interleaved 8B record per edge: halves scattered-line touches vs 2x4B
__global__ __launch_bounds__(256) void fill_kernel(const int* __restrict__ ei,
                                                   const float* __restrict__ ew,
                                                   const int* __restrict__ off,
                                                   int* __restrict__ cur,
                                                   int2* __restrict__ srt) {
  int e = blockIdx.x * 256 + threadIdx.x;
  if (e >= N_EDGES) return;
  int dst = ei[e];
  int p = off[dst] + atomicAdd(&cur[dst], 1);
  srt[p] = make_int2(ei[N_EDGES + e], __float_as_int(ew[e]));
}

// ================= bf16 conversion of x =================

__device__ __forceinline__ unsigned bf16rne(float f) {
  unsigned u = __float_as_uint(f);
  return (u + 0x7fffu + ((u >> 16) & 1u)) >> 16;
}

__global__ __launch_bounds__(256) void convert_kernel(const float* __restrict__ x,
                                                      uint4* __restrict__ xh) {
  int i = blockIdx.x * 256 + threadIdx.x;  // exactly N*D/8 = 1.6M threads
  const float4* xp = reinterpret_cast<const float4*>(x);
  float4 a = xp[(size_t)i * 2];
  float4 b = xp[(size_t)i * 2 + 1];
  uint4 o;
  o.x = bf16rne(a.x) | (bf16rne(a.y) << 16);
  o.y = bf16rne(a.z) | (bf16rne(a.w) << 16);
  o.z = bf16rne(b.x) | (bf16rne(b.y) << 16);
  o.w = bf16rne(b.z) | (bf16rne(b.w) << 16);
  xh[i] = o;
}

// ================= gather (bf16 rows, 2-edge unroll) =================

__global__ __launch_bounds__(256) void gather_bf16_kernel(const unsigned* __restrict__ xh,
                                                          const int* __restrict__ off,
                                                          const int2* __restrict__ srt,
                                                          float* __restrict__ z,
                                                          float* __restrict__ degf) {
  int gid = blockIdx.x * 256 + threadIdx.x;
  int n = gid >> 5;
  int lane = gid & 31;
  if (n >= N_NODES) return;
  int beg = off[n], end = off[n + 1];
  float4 acc = make_float4(0.f, 0.f, 0.f, 0.f);
  int e = beg;
  for (; e + 1 < end; e += 2) {
    int2 r0 = srt[e];
    int2 r1 = srt[e + 1];
    uint2 p0 = *reinterpret_cast<const uint2*>(xh + (size_t)r0.x * 64 + lane * 2);
    uint2 p1 = *reinterpret_cast<const uint2*>(xh + (size_t)r1.x * 64 + lane * 2);
    float w0 = __int_as_float(r0.y);
    float w1 = __int_as_float(r1.y);
    acc.x = fmaf(w0, __uint_as_float(p0.x << 16), acc.x);
    acc.y = fmaf(w0, __uint_as_float(p0.x & 0xffff0000u), acc.y);
    acc.z = fmaf(w0, __uint_as_float(p0.y << 16), acc.z);
    acc.w = fmaf(w0, __uint_as_float(p0.y & 0xffff0000u), acc.w);
    acc.x = fmaf(w1, __uint_as_float(p1.x << 16), acc.x);
    acc.y = fmaf(w1, __uint_as_float(p1.x & 0xffff0000u), acc.y);
    acc.z = fmaf(w1, __uint_as_float(p1.y << 16), acc.z);
    acc.w = fmaf(w1, __uint_as_float(p1.y & 0xffff0000u), acc.w);
  }
  if (e < end) {
    int2 r0 = srt[e];
    uint2 p0 = *reinterpret_cast<const uint2*>(xh + (size_t)r0.x * 64 + lane * 2);
    float w0 = __int_as_float(r0.y);
    acc.x = fmaf(w0, __uint_as_float(p0.x << 16), acc.x);
    acc.y = fmaf(w0, __uint_as_float(p0.x & 0xffff0000u), acc.y);
    acc.z = fmaf(w0, __uint_as_float(p0.y << 16), acc.z);
    acc.w = fmaf(w0, __uint_as_float(p0.y & 0xffff0000u), acc.w);
  }
  *reinterpret_cast<float4*>(z + (size_t)n * D + (lane << 2)) = acc;
  if (lane == 0) degf[n] = (float)(end - beg);
}

// fp32 fallback gather (tier 1: no room for xh)
__global__ __launch_bounds__(256) void gather_f32_kernel(const float* __restrict__ x,
                                                         const int* __restrict__ off,
                                                         const int2* __restrict__ srt,
                                                         float* __restrict__ z,
                                                         float* __restrict__ degf) {
  int gid = blockIdx.x * 256 + threadIdx.x;
  int n = gid >> 5;
  int lane = gid & 31;
  if (n >= N_NODES) return;
  int beg = off[n], end = off[n + 1];
  float4 acc = make_float4(0.f, 0.f, 0.f, 0.f);
  int e = beg;
  for (; e + 1 < end; e += 2) {
    int2 r0 = srt[e];
    int2 r1 = srt[e + 1];
    float4 x0 = *reinterpret_cast<const float4*>(x + (size_t)r0.x * D + (lane << 2));
    float4 x1 = *reinterpret_cast<const float4*>(x + (size_t)r1.x * D + (lane << 2));
    float w0 = __int_as_float(r0.y);
    float w1 = __int_as_float(r1.y);
    acc.x = fmaf(w0, x0.x, acc.x); acc.y = fmaf(w0, x0.y, acc.y);
    acc.z = fmaf(w0, x0.z, acc.z); acc.w = fmaf(w0, x0.w, acc.w);
    acc.x = fmaf(w1, x1.x, acc.x); acc.y = fmaf(w1, x1.y, acc.y);
    acc.z = fmaf(w1, x1.z, acc.z); acc.w = fmaf(w1, x1.w, acc.w);
  }
  if (e < end) {
    int2 r0 = srt[e];
    float4 x0 = *reinterpret_cast<const float4*>(x + (size_t)r0.x * D + (lane << 2));
    float w0 = __int_as_float(r0.y);
    acc.x = fmaf(w0, x0.x, acc.x); acc.y = fmaf(w0, x0.y, acc.y);
    acc.z = fmaf(w0, x0.z, acc.z); acc.w = fmaf(w0, x0.w, acc.w);
  }
  *reinterpret_cast<float4*>(z + (size_t)n * D + (lane << 2)) = acc;
  if (lane == 0) degf[n] = (float)(end - beg);
}

// ================= atomic fallback (tiny ws) =================

__global__ __launch_bounds__(256) void scatter_kernel(const float* __restrict__ x,
                                                      const int* __restrict__ ei,
                                                      const float* __restrict__ ew,
                                                      float* __restrict__ z,
                                                      float* __restrict__ deg) {
  long long g = (long long)blockIdx.x * 256 + threadIdx.x;
  int e = (int)(g >> 5);
  int lane = (int)(g & 31);
  if (e >= N_EDGES) return;
  int dst = ei[e];
  int src = ei[N_EDGES + e];
  float w = ew[e];
  float4 xv = *reinterpret_cast<const float4*>(x + (size_t)src * D + (lane << 2));
  float* o = z + (size_t)dst * D + (lane << 2);
  atomicAdd(o + 0, w * xv.x);
  atomicAdd(o + 1, w * xv.y);
  atomicAdd(o + 2, w * xv.z);
  atomicAdd(o + 3, w * xv.w);
  if (lane == 0) atomicAdd(deg + dst, 1.0f);
}

// ================= fused double-GEMM =================
// out[r] = x[r]@W_lin + b_lin + z[r]@W_agg + deg[r]*b_agg ; z read from `out`

__global__ __launch_bounds__(256) void fused_gemm_kernel(const float* __restrict__ x,
                                                         const float* __restrict__ Wl,
                                                         const float* __restrict__ bl,
                                                         const float* __restrict__ Wa,
                                                         const float* __restrict__ ba,
                                                         const float* __restrict__ deg,
                                                         float* __restrict__ out) {
  __shared__ float xs[32 * 16];
  __shared__ float zs[32 * 16];
  __shared__ float wls[16 * 128];
  __shared__ float was[16 * 128];
  const int tid = threadIdx.x;
  const int row0 = blockIdx.x * 32;
  const int c4 = tid & 31;
  const int r0 = tid >> 5;
  float4 acc[4];
#pragma unroll
  for (int i = 0; i < 4; i++) acc[i] = make_float4(0.f, 0.f, 0.f, 0.f);

  for (int k0 = 0; k0 < D; k0 += 16) {
    {
      int t = tid & 127;
      int r = t >> 2;
      int kc = (t & 3) << 2;
      const float* sp = (tid < 128) ? x : out;
      float* dp = (tid < 128) ? xs : zs;
      *reinterpret_cast<float4*>(dp + r * 16 + kc) =
          *reinterpret_cast<const float4*>(sp + (size_t)(row0 + r) * D + k0 + kc);
    }
#pragma unroll
    for (int i = 0; i < 2; i++) {
      int f = tid + i * 256;
      int kk = f >> 5;
      int cc = (f & 31) << 2;
      *reinterpret_cast<float4*>(wls + kk * 128 + cc) =
          *reinterpret_cast<const float4*>(Wl + (size_t)(k0 + kk) * D + cc);
      *reinterpret_cast<float4*>(was + kk * 128 + cc) =
          *reinterpret_cast<const float4*>(Wa + (size_t)(k0 + kk) * D + cc);
    }
    __syncthreads();
#pragma unroll
    for (int kk = 0; kk < 16; kk++) {
      float4 wl = *reinterpret_cast<const float4*>(wls + kk * 128 + (c4 << 2));
      float4 wa = *reinterpret_cast<const float4*>(was + kk * 128 + (c4 << 2));
#pragma unroll
      for (int rr = 0; rr < 4; rr++) {
        int r2 = r0 + rr * 8;
        float xv = xs[r2 * 16 + kk];
        float zv = zs[r2 * 16 + kk];
        acc[rr].x = fmaf(xv, wl.x, fmaf(zv, wa.x, acc[rr].x));
        acc[rr].y = fmaf(xv, wl.y, fmaf(zv, wa.y, acc[rr].y));
        acc[rr].z = fmaf(xv, wl.z, fmaf(zv, wa.z, acc[rr].z));
        acc[rr].w = fmaf(xv, wl.w, fmaf(zv, wa.w, acc[rr].w));
      }
    }
    __syncthreads();
  }

  float4 blv = *reinterpret_cast<const float4*>(bl + (c4 << 2));
  float4 bav = *reinterpret_cast<const float4*>(ba + (c4 << 2));
#pragma unroll
  for (int rr = 0; rr < 4; rr++) {
    int r = row0 + r0 + rr * 8;
    float d = deg[r];
    float4 o;
    o.x = acc[rr].x + blv.x + d * bav.x;
    o.y = acc[rr].y + blv.y + d * bav.y;
    o.z = acc[rr].z + blv.z + d * bav.z;
    o.w = acc[rr].w + blv.w + d * bav.w;
    *reinterpret_cast<float4*>(out + (size_t)r * D + (c4 << 2)) = o;
  }
}

extern "C" void kernel_launch(void* const* d_in, const int* in_sizes, int n_in,
                              void* d_out, int out_size, void* d_ws, size_t ws_size,
                              hipStream_t stream) {
  const float* x  = (const float*)d_in[0];
  const int*   ei = (const int*)d_in[1];
  const float* ew = (const float*)d_in[2];
  const float* Wl = (const float*)d_in[3];
  const float* bl = (const float*)d_in[4];
  const float* Wa = (const float*)d_in[5];
  const float* ba = (const float*)d_in[6];
  float* out = (float*)d_out;

  if (ws_size >= WS_T1_BYTES) {
    int*  cnt  = (int*)d_ws;
    int*  off  = cnt + WS_OFF;
    int*  bsum = cnt + WS_BSUM;
    int2* srt  = (int2*)(cnt + WS_SRT);
    float* degf = (float*)cnt;  // aliased; cnt dead after fill

    hipMemsetAsync(cnt, 0, (size_t)N_NODES * sizeof(int), stream);
    hist_kernel<<<(N_EDGES + 255) / 256, 256, 0, stream>>>(ei, cnt);
    block_sum_kernel<<<NB_SCAN, 256, 0, stream>>>(cnt, bsum);
    scan_bsum_kernel<<<1, 128, 0, stream>>>(bsum, off);
    scan_offsets_kernel<<<NB_SCAN, 256, 0, stream>>>(cnt, bsum, off);
    hipMemsetAsync(cnt, 0, (size_t)N_NODES * sizeof(int), stream);
    fill_kernel<<<(N_EDGES + 255) / 256, 256, 0, stream>>>(ei, ew, off, cnt, srt);

    if (ws_size >= WS_T2_BYTES) {
      unsigned* xh = (unsigned*)(cnt + WS_XH);
      convert_kernel<<<(N_NODES * D / 8) / 256, 256, 0, stream>>>(x, (uint4*)xh);
      gather_bf16_kernel<<<(N_NODES * 32 + 255) / 256, 256, 0, stream>>>(xh, off, srt, out, degf);
    } else {
      gather_f32_kernel<<<(N_NODES * 32 + 255) / 256, 256, 0, stream>>>(x, off, srt, out, degf);
    }
    fused_gemm_kernel<<<N_NODES / 32, 256, 0, stream>>>(x, Wl, bl, Wa, ba, degf, out);
  } else {
    float* deg = (float*)d_ws;
    hipMemsetAsync(out, 0, (size_t)N_NODES * D * sizeof(float), stream);
    hipMemsetAsync(deg, 0, (size_t)N_NODES * sizeof(float), stream);
    scatter_kernel<<<(N_EDGES * 32) / 256, 256, 0, stream>>>(x, ei, ew, out, deg);
    fused_gemm_kernel<<<N_NODES / 32, 256, 0, stream>>>(x, Wl, bl, Wa, ba, deg, out);
  }
}

// Round 4
// 400.549 us; speedup vs baseline: 7.3682x; 1.1374x over previous
//
#include <hip/hip_runtime.h>

#define N_NODES 100000
#define N_EDGES 1600000
#define D 128
#define SCAN_CHUNK 1024
#define NB_SCAN ((N_NODES + SCAN_CHUNK - 1) / SCAN_CHUNK)  // 98

typedef __attribute__((ext_vector_type(8))) short bf16x8;
typedef __attribute__((ext_vector_type(4))) float f32x4;

__device__ __forceinline__ unsigned bf16rne(float f) {
  unsigned u = __float_as_uint(f);
  return (u + 0x7fffu + ((u >> 16) & 1u)) >> 16;
}

// ================= Tier-3 layout (int units) =================
// cnt   [0,100000)          histogram -> cursor (in-place after scan)
// off   [100000,200004)     CSR offsets (100001)
// bsum  [200004,200102)     per-block sums
// fragW [200104,216488)     swizzled bf16 B-fragments (32768 bf16)
// srt   [216488,3416488)    int2 {src,w} sorted by dst
// xh    [3416488,9818536)   x bf16, padded to 100032 rows
// zh    [9818536,16220584)  z bf16, padded to 100032 rows
#define T3_OFF    100000
#define T3_BSUM   200004
#define T3_FRAGW  200104
#define T3_SRT    216488
#define T3_XH     3416488
#define T3_ZH     9818536
#define WS_T3_BYTES ((size_t)16220584 * 4)

// ---- old tier layouts (round-3 fallback) ----
#define WS_OFF   100000
#define WS_BSUM  200004
#define WS_SRT   200192
#define WS_XH    3400192
#define WS_T1_BYTES ((size_t)3400192 * 4)
#define WS_T2_BYTES ((size_t)(3400192 + 6400000) * 4)

// ================= T3: fused hist + x->bf16 + W swizzle =================
// blocks [0,6250): edge e -> hist atomic; group e -> convert 8 floats of x.
// blocks [6250,6378): one W element each -> bf16 frag buffer, MFMA-B swizzled:
//   frag slot (s,t,lane) holds B[k = (s%4)*32 + (lane>>4)*8 + j][n = t*16 + (lane&15)]
//   (s<4 from W_lin, s>=4 from W_agg), j contiguous -> 16B per lane.
__global__ __launch_bounds__(256) void histconv_kernel(
    const int* __restrict__ ei, const float* __restrict__ x,
    const float* __restrict__ Wl, const float* __restrict__ Wa,
    int* __restrict__ cnt, uint4* __restrict__ xh4,
    unsigned short* __restrict__ fragW) {
  int bid = blockIdx.x;
  if (bid < N_EDGES / 256) {
    int e = bid * 256 + threadIdx.x;
    atomicAdd(&cnt[ei[e]], 1);
    const float4* xp = reinterpret_cast<const float4*>(x);
    float4 a = xp[(size_t)e * 2];
    float4 b = xp[(size_t)e * 2 + 1];
    uint4 o;
    o.x = bf16rne(a.x) | (bf16rne(a.y) << 16);
    o.y = bf16rne(a.z) | (bf16rne(a.w) << 16);
    o.z = bf16rne(b.x) | (bf16rne(b.y) << 16);
    o.w = bf16rne(b.z) | (bf16rne(b.w) << 16);
    xh4[e] = o;
  } else {
    int tau = (bid - N_EDGES / 256) * 256 + threadIdx.x;  // 0..32767
    int slot = tau >> 3, j = tau & 7;
    int lane = slot & 63, ft = slot >> 6;
    int t = ft & 7, s = ft >> 3;
    int kl = (s & 3) * 32 + (lane >> 4) * 8 + j;
    int n = t * 16 + (lane & 15);
    float v = (s < 4 ? Wl : Wa)[kl * 128 + n];
    fragW[slot * 8 + j] = (unsigned short)bf16rne(v);
  }
}

__global__ __launch_bounds__(256) void block_sum_kernel(const int* __restrict__ cnt,
                                                        int* __restrict__ bsum) {
  int base = blockIdx.x * SCAN_CHUNK;
  int s = 0;
#pragma unroll
  for (int k = 0; k < 4; k++) {
    int i = base + (int)threadIdx.x + k * 256;
    if (i < N_NODES) s += cnt[i];
  }
  __shared__ int red[4];
  for (int o = 32; o > 0; o >>= 1) s += __shfl_down(s, o, 64);
  if ((threadIdx.x & 63) == 0) red[threadIdx.x >> 6] = s;
  __syncthreads();
  if (threadIdx.x == 0) bsum[blockIdx.x] = red[0] + red[1] + red[2] + red[3];
}

// T3: scan chunk; every block redundantly scans the 98 bsums in LDS.
// Writes off[] (preserved) and cnt[] (becomes the fill cursor).
__global__ __launch_bounds__(256) void scan2_kernel(int* __restrict__ cnt,
                                                    const int* __restrict__ bsum,
                                                    int* __restrict__ off) {
  __shared__ int sb[NB_SCAN + 1];
  __shared__ int sh[256];
  int t = threadIdx.x;
  if (t < NB_SCAN) sb[t] = bsum[t];
  __syncthreads();
  if (t == 0) {
    int run = 0;
    for (int i = 0; i < NB_SCAN; i++) { int c = sb[i]; sb[i] = run; run += c; }
    sb[NB_SCAN] = run;
  }
  __syncthreads();
  int i0 = blockIdx.x * SCAN_CHUNK + t * 4;
  int c[4];
#pragma unroll
  for (int k = 0; k < 4; k++) c[k] = (i0 + k < N_NODES) ? cnt[i0 + k] : 0;
  int ls = c[0] + c[1] + c[2] + c[3];
  sh[t] = ls;
  __syncthreads();
  for (int o = 1; o < 256; o <<= 1) {
    int add = (t >= o) ? sh[t - o] : 0;
    __syncthreads();
    sh[t] += add;
    __syncthreads();
  }
  int run = sb[blockIdx.x] + sh[t] - ls;
#pragma unroll
  for (int k = 0; k < 4; k++) {
    if (i0 + k < N_NODES) { off[i0 + k] = run; cnt[i0 + k] = run; run += c[k]; }
  }
  if (blockIdx.x == 0 && t == 0) off[N_NODES] = sb[NB_SCAN];
}

// T3 fill: cursor IS the scanned cnt (atomicAdd returns the slot directly)
__global__ __launch_bounds__(256) void fill2_kernel(const int* __restrict__ ei,
                                                    const float* __restrict__ ew,
                                                    int* __restrict__ cur,
                                                    int2* __restrict__ srt) {
  int e = blockIdx.x * 256 + threadIdx.x;
  int dst = ei[e];
  int p = atomicAdd(&cur[dst], 1);
  srt[p] = make_int2(ei[N_EDGES + e], __float_as_int(ew[e]));
}

// T3 gather: bf16 x rows in, bf16 z rows out (half-wave per node)
__global__ __launch_bounds__(256) void gather_zh_kernel(const unsigned* __restrict__ xh,
                                                        const int* __restrict__ off,
                                                        const int2* __restrict__ srt,
                                                        unsigned* __restrict__ zh) {
  int gid = blockIdx.x * 256 + threadIdx.x;
  int n = gid >> 5;
  int lane = gid & 31;
  int beg = off[n], end = off[n + 1];
  float4 acc = make_float4(0.f, 0.f, 0.f, 0.f);
  int e = beg;
  for (; e + 1 < end; e += 2) {
    int2 r0 = srt[e];
    int2 r1 = srt[e + 1];
    uint2 p0 = *reinterpret_cast<const uint2*>(xh + (size_t)r0.x * 64 + lane * 2);
    uint2 p1 = *reinterpret_cast<const uint2*>(xh + (size_t)r1.x * 64 + lane * 2);
    float w0 = __int_as_float(r0.y);
    float w1 = __int_as_float(r1.y);
    acc.x = fmaf(w0, __uint_as_float(p0.x << 16), acc.x);
    acc.y = fmaf(w0, __uint_as_float(p0.x & 0xffff0000u), acc.y);
    acc.z = fmaf(w0, __uint_as_float(p0.y << 16), acc.z);
    acc.w = fmaf(w0, __uint_as_float(p0.y & 0xffff0000u), acc.w);
    acc.x = fmaf(w1, __uint_as_float(p1.x << 16), acc.x);
    acc.y = fmaf(w1, __uint_as_float(p1.x & 0xffff0000u), acc.y);
    acc.z = fmaf(w1, __uint_as_float(p1.y << 16), acc.z);
    acc.w = fmaf(w1, __uint_as_float(p1.y & 0xffff0000u), acc.w);
  }
  if (e < end) {
    int2 r0 = srt[e];
    uint2 p0 = *reinterpret_cast<const uint2*>(xh + (size_t)r0.x * 64 + lane * 2);
    float w0 = __int_as_float(r0.y);
    acc.x = fmaf(w0, __uint_as_float(p0.x << 16), acc.x);
    acc.y = fmaf(w0, __uint_as_float(p0.x & 0xffff0000u), acc.y);
    acc.z = fmaf(w0, __uint_as_float(p0.y << 16), acc.z);
    acc.w = fmaf(w0, __uint_as_float(p0.y & 0xffff0000u), acc.w);
  }
  uint2 o;
  o.x = bf16rne(acc.x) | (bf16rne(acc.y) << 16);
  o.y = bf16rne(acc.z) | (bf16rne(acc.w) << 16);
  *reinterpret_cast<uint2*>(zh + (size_t)n * 64 + lane * 2) = o;
}

// T3 MFMA GEMM: out = [xh|zh] @ [Wl;Wa] + bl + deg*ba.
// Block = 64 rows (4 waves x 16), wave covers all 128 cols via 8 N-tiles.
// A frags straight from global (16B/lane); B frags from pre-swizzled buffer.
__global__ __launch_bounds__(256) void mfma_gemm_kernel(
    const short* __restrict__ xh, const short* __restrict__ zh,
    const short* __restrict__ fragW, const int* __restrict__ off,
    const float* __restrict__ bl, const float* __restrict__ ba,
    float* __restrict__ out) {
  int tid = threadIdx.x;
  int wave = tid >> 6, lane = tid & 63;
  int m = lane & 15, q = lane >> 4;
  int R = blockIdx.x * 64 + wave * 16;
  const short* xrow = xh + (size_t)(R + m) * D + q * 8;
  const short* zrow = zh + (size_t)(R + m) * D + q * 8;
  const short* fw = fragW + (size_t)lane * 8;

  f32x4 acc[8];
#pragma unroll
  for (int t = 0; t < 8; t++) acc[t] = (f32x4){0.f, 0.f, 0.f, 0.f};

#pragma unroll
  for (int s = 0; s < 8; s++) {
    bf16x8 a = *reinterpret_cast<const bf16x8*>(s < 4 ? xrow + s * 32
                                                      : zrow + (s - 4) * 32);
#pragma unroll
    for (int t = 0; t < 8; t++) {
      bf16x8 b = *reinterpret_cast<const bf16x8*>(fw + (size_t)((s * 8 + t) * 64) * 8);
      acc[t] = __builtin_amdgcn_mfma_f32_16x16x32_bf16(a, b, acc[t], 0, 0, 0);
    }
  }

  float blv[8], bav[8];
#pragma unroll
  for (int t = 0; t < 8; t++) {
    blv[t] = bl[t * 16 + m];
    bav[t] = ba[t * 16 + m];
  }
#pragma unroll
  for (int r = 0; r < 4; r++) {
    int row = R + q * 4 + r;
    if (row < N_NODES) {
      float dg = (float)(off[row + 1] - off[row]);
#pragma unroll
      for (int t = 0; t < 8; t++)
        out[(size_t)row * D + t * 16 + m] = acc[t][r] + blv[t] + dg * bav[t];
    }
  }
}

// ================= round-3 fallback kernels (tiers 0-2) =================

__global__ __launch_bounds__(256) void hist_kernel(const int* __restrict__ ei,
                                                   int* __restrict__ cnt) {
  int e = blockIdx.x * 256 + threadIdx.x;
  if (e < N_EDGES) atomicAdd(&cnt[ei[e]], 1);
}

__global__ __launch_bounds__(128) void scan_bsum_kernel(int* __restrict__ bsum,
                                                        int* __restrict__ off) {
  __shared__ int sh[128];
  int t = threadIdx.x;
  int v = (t < NB_SCAN) ? bsum[t] : 0;
  sh[t] = v;
  __syncthreads();
  for (int o = 1; o < 128; o <<= 1) {
    int add = (t >= o) ? sh[t - o] : 0;
    __syncthreads();
    sh[t] += add;
    __syncthreads();
  }
  if (t < NB_SCAN) bsum[t] = sh[t] - v;
  if (t == 0) off[N_NODES] = sh[127];
}

__global__ __launch_bounds__(256) void scan_offsets_kernel(const int* __restrict__ cnt,
                                                           const int* __restrict__ bsum,
                                                           int* __restrict__ off) {
  __shared__ int sh[256];
  int t = threadIdx.x;
  int i0 = blockIdx.x * SCAN_CHUNK + t * 4;
  int c[4];
#pragma unroll
  for (int k = 0; k < 4; k++) c[k] = (i0 + k < N_NODES) ? cnt[i0 + k] : 0;
  int ls = c[0] + c[1] + c[2] + c[3];
  sh[t] = ls;
  __syncthreads();
  for (int o = 1; o < 256; o <<= 1) {
    int add = (t >= o) ? sh[t - o] : 0;
    __syncthreads();
    sh[t] += add;
    __syncthreads();
  }
  int run = bsum[blockIdx.x] + sh[t] - ls;
#pragma unroll
  for (int k = 0; k < 4; k++) {
    if (i0 + k < N_NODES) off[i0 + k] = run;
    run += c[k];
  }
}

__global__ __launch_bounds__(256) void fill_kernel(const int* __restrict__ ei,
                                                   const float* __restrict__ ew,
                                                   const int* __restrict__ off,
                                                   int* __restrict__ cur,
                                                   int2* __restrict__ srt) {
  int e = blockIdx.x * 256 + threadIdx.x;
  if (e >= N_EDGES) return;
  int dst = ei[e];
  int p = off[dst] + atomicAdd(&cur[dst], 1);
  srt[p] = make_int2(ei[N_EDGES + e], __float_as_int(ew[e]));
}

__global__ __launch_bounds__(256) void convert_kernel(const float* __restrict__ x,
                                                      uint4* __restrict__ xh) {
  int i = blockIdx.x * 256 + threadIdx.x;
  const float4* xp = reinterpret_cast<const float4*>(x);
  float4 a = xp[(size_t)i * 2];
  float4 b = xp[(size_t)i * 2 + 1];
  uint4 o;
  o.x = bf16rne(a.x) | (bf16rne(a.y) << 16);
  o.y = bf16rne(a.z) | (bf16rne(a.w) << 16);
  o.z = bf16rne(b.x) | (bf16rne(b.y) << 16);
  o.w = bf16rne(b.z) | (bf16rne(b.w) << 16);
  xh[i] = o;
}

__global__ __launch_bounds__(256) void gather_bf16_kernel(const unsigned* __restrict__ xh,
                                                          const int* __restrict__ off,
                                                          const int2* __restrict__ srt,
                                                          float* __restrict__ z,
                                                          float* __restrict__ degf) {
  int gid = blockIdx.x * 256 + threadIdx.x;
  int n = gid >> 5;
  int lane = gid & 31;
  if (n >= N_NODES) return;
  int beg = off[n], end = off[n + 1];
  float4 acc = make_float4(0.f, 0.f, 0.f, 0.f);
  int e = beg;
  for (; e + 1 < end; e += 2) {
    int2 r0 = srt[e];
    int2 r1 = srt[e + 1];
    uint2 p0 = *reinterpret_cast<const uint2*>(xh + (size_t)r0.x * 64 + lane * 2);
    uint2 p1 = *reinterpret_cast<const uint2*>(xh + (size_t)r1.x * 64 + lane * 2);
    float w0 = __int_as_float(r0.y);
    float w1 = __int_as_float(r1.y);
    acc.x = fmaf(w0, __uint_as_float(p0.x << 16), acc.x);
    acc.y = fmaf(w0, __uint_as_float(p0.x & 0xffff0000u), acc.y);
    acc.z = fmaf(w0, __uint_as_float(p0.y << 16), acc.z);
    acc.w = fmaf(w0, __uint_as_float(p0.y & 0xffff0000u), acc.w);
    acc.x = fmaf(w1, __uint_as_float(p1.x << 16), acc.x);
    acc.y = fmaf(w1, __uint_as_float(p1.x & 0xffff0000u), acc.y);
    acc.z = fmaf(w1, __uint_as_float(p1.y << 16), acc.z);
    acc.w = fmaf(w1, __uint_as_float(p1.y & 0xffff0000u), acc.w);
  }
  if (e < end) {
    int2 r0 = srt[e];
    uint2 p0 = *reinterpret_cast<const uint2*>(xh + (size_t)r0.x * 64 + lane * 2);
    float w0 = __int_as_float(r0.y);
    acc.x = fmaf(w0, __uint_as_float(p0.x << 16), acc.x);
    acc.y = fmaf(w0, __uint_as_float(p0.x & 0xffff0000u), acc.y);
    acc.z = fmaf(w0, __uint_as_float(p0.y << 16), acc.z);
    acc.w = fmaf(w0, __uint_as_float(p0.y & 0xffff0000u), acc.w);
  }
  *reinterpret_cast<float4*>(z + (size_t)n * D + (lane << 2)) = acc;
  if (lane == 0) degf[n] = (float)(end - beg);
}

__global__ __launch_bounds__(256) void gather_f32_kernel(const float* __restrict__ x,
                                                         const int* __restrict__ off,
                                                         const int2* __restrict__ srt,
                                                         float* __restrict__ z,
                                                         float* __restrict__ degf) {
  int gid = blockIdx.x * 256 + threadIdx.x;
  int n = gid >> 5;
  int lane = gid & 31;
  if (n >= N_NODES) return;
  int beg = off[n], end = off[n + 1];
  float4 acc = make_float4(0.f, 0.f, 0.f, 0.f);
  int e = beg;
  for (; e + 1 < end; e += 2) {
    int2 r0 = srt[e];
    int2 r1 = srt[e + 1];
    float4 x0 = *reinterpret_cast<const float4*>(x + (size_t)r0.x * D + (lane << 2));
    float4 x1 = *reinterpret_cast<const float4*>(x + (size_t)r1.x * D + (lane << 2));
    float w0 = __int_as_float(r0.y);
    float w1 = __int_as_float(r1.y);
    acc.x = fmaf(w0, x0.x, acc.x); acc.y = fmaf(w0, x0.y, acc.y);
    acc.z = fmaf(w0, x0.z, acc.z); acc.w = fmaf(w0, x0.w, acc.w);
    acc.x = fmaf(w1, x1.x, acc.x); acc.y = fmaf(w1, x1.y, acc.y);
    acc.z = fmaf(w1, x1.z, acc.z); acc.w = fmaf(w1, x1.w, acc.w);
  }
  if (e < end) {
    int2 r0 = srt[e];
    float4 x0 = *reinterpret_cast<const float4*>(x + (size_t)r0.x * D + (lane << 2));
    float w0 = __int_as_float(r0.y);
    acc.x = fmaf(w0, x0.x, acc.x); acc.y = fmaf(w0, x0.y, acc.y);
    acc.z = fmaf(w0, x0.z, acc.z); acc.w = fmaf(w0, x0.w, acc.w);
  }
  *reinterpret_cast<float4*>(z + (size_t)n * D + (lane << 2)) = acc;
  if (lane == 0) degf[n] = (float)(end - beg);
}

__global__ __launch_bounds__(256) void scatter_kernel(const float* __restrict__ x,
                                                      const int* __restrict__ ei,
                                                      const float* __restrict__ ew,
                                                      float* __restrict__ z,
                                                      float* __restrict__ deg) {
  long long g = (long long)blockIdx.x * 256 + threadIdx.x;
  int e = (int)(g >> 5);
  int lane = (int)(g & 31);
  if (e >= N_EDGES) return;
  int dst = ei[e];
  int src = ei[N_EDGES + e];
  float w = ew[e];
  float4 xv = *reinterpret_cast<const float4*>(x + (size_t)src * D + (lane << 2));
  float* o = z + (size_t)dst * D + (lane << 2);
  atomicAdd(o + 0, w * xv.x);
  atomicAdd(o + 1, w * xv.y);
  atomicAdd(o + 2, w * xv.z);
  atomicAdd(o + 3, w * xv.w);
  if (lane == 0) atomicAdd(deg + dst, 1.0f);
}

__global__ __launch_bounds__(256) void fused_gemm_kernel(const float* __restrict__ x,
                                                         const float* __restrict__ Wl,
                                                         const float* __restrict__ bl,
                                                         const float* __restrict__ Wa,
                                                         const float* __restrict__ ba,
                                                         const float* __restrict__ deg,
                                                         float* __restrict__ out) {
  __shared__ float xs[32 * 16];
  __shared__ float zs[32 * 16];
  __shared__ float wls[16 * 128];
  __shared__ float was[16 * 128];
  const int tid = threadIdx.x;
  const int row0 = blockIdx.x * 32;
  const int c4 = tid & 31;
  const int r0 = tid >> 5;
  float4 acc[4];
#pragma unroll
  for (int i = 0; i < 4; i++) acc[i] = make_float4(0.f, 0.f, 0.f, 0.f);

  for (int k0 = 0; k0 < D; k0 += 16) {
    {
      int t = tid & 127;
      int r = t >> 2;
      int kc = (t & 3) << 2;
      const float* sp = (tid < 128) ? x : out;
      float* dp = (tid < 128) ? xs : zs;
      *reinterpret_cast<float4*>(dp + r * 16 + kc) =
          *reinterpret_cast<const float4*>(sp + (size_t)(row0 + r) * D + k0 + kc);
    }
#pragma unroll
    for (int i = 0; i < 2; i++) {
      int f = tid + i * 256;
      int kk = f >> 5;
      int cc = (f & 31) << 2;
      *reinterpret_cast<float4*>(wls + kk * 128 + cc) =
          *reinterpret_cast<const float4*>(Wl + (size_t)(k0 + kk) * D + cc);
      *reinterpret_cast<float4*>(was + kk * 128 + cc) =
          *reinterpret_cast<const float4*>(Wa + (size_t)(k0 + kk) * D + cc);
    }
    __syncthreads();
#pragma unroll
    for (int kk = 0; kk < 16; kk++) {
      float4 wl = *reinterpret_cast<const float4*>(wls + kk * 128 + (c4 << 2));
      float4 wa = *reinterpret_cast<const float4*>(was + kk * 128 + (c4 << 2));
#pragma unroll
      for (int rr = 0; rr < 4; rr++) {
        int r2 = r0 + rr * 8;
        float xv = xs[r2 * 16 + kk];
        float zv = zs[r2 * 16 + kk];
        acc[rr].x = fmaf(xv, wl.x, fmaf(zv, wa.x, acc[rr].x));
        acc[rr].y = fmaf(xv, wl.y, fmaf(zv, wa.y, acc[rr].y));
        acc[rr].z = fmaf(xv, wl.z, fmaf(zv, wa.z, acc[rr].z));
        acc[rr].w = fmaf(xv, wl.w, fmaf(zv, wa.w, acc[rr].w));
      }
    }
    __syncthreads();
  }

  float4 blv = *reinterpret_cast<const float4*>(bl + (c4 << 2));
  float4 bav = *reinterpret_cast<const float4*>(ba + (c4 << 2));
#pragma unroll
  for (int rr = 0; rr < 4; rr++) {
    int r = row0 + r0 + rr * 8;
    float d = deg[r];
    float4 o;
    o.x = acc[rr].x + blv.x + d * bav.x;
    o.y = acc[rr].y + blv.y + d * bav.y;
    o.z = acc[rr].z + blv.z + d * bav.z;
    o.w = acc[rr].w + blv.w + d * bav.w;
    *reinterpret_cast<float4*>(out + (size_t)r * D + (c4 << 2)) = o;
  }
}

extern "C" void kernel_launch(void* const* d_in, const int* in_sizes, int n_in,
                              void* d_out, int out_size, void* d_ws, size_t ws_size,
                              hipStream_t stream) {
  const float* x  = (const float*)d_in[0];
  const int*   ei = (const int*)d_in[1];
  const float* ew = (const float*)d_in[2];
  const float* Wl = (const float*)d_in[3];
  const float* bl = (const float*)d_in[4];
  const float* Wa = (const float*)d_in[5];
  const float* ba = (const float*)d_in[6];
  float* out = (float*)d_out;

  if (ws_size >= WS_T3_BYTES) {
    int* cnt = (int*)d_ws;
    int* off = cnt + T3_OFF;
    int* bsum = cnt + T3_BSUM;
    unsigned short* fragW = (unsigned short*)(cnt + T3_FRAGW);
    int2* srt = (int2*)(cnt + T3_SRT);
    unsigned* xh = (unsigned*)(cnt + T3_XH);
    unsigned* zh = (unsigned*)(cnt + T3_ZH);

    hipMemsetAsync(cnt, 0, (size_t)N_NODES * sizeof(int), stream);
    histconv_kernel<<<N_EDGES / 256 + 128, 256, 0, stream>>>(ei, x, Wl, Wa, cnt,
                                                             (uint4*)xh, fragW);
    block_sum_kernel<<<NB_SCAN, 256, 0, stream>>>(cnt, bsum);
    scan2_kernel<<<NB_SCAN, 256, 0, stream>>>(cnt, bsum, off);
    fill2_kernel<<<N_EDGES / 256, 256, 0, stream>>>(ei, ew, cnt, srt);
    gather_zh_kernel<<<N_NODES * 32 / 256, 256, 0, stream>>>(xh, off, srt, zh);
    mfma_gemm_kernel<<<1563, 256, 0, stream>>>((const short*)xh, (const short*)zh,
                                               (const short*)fragW, off, bl, ba, out);
  } else if (ws_size >= WS_T1_BYTES) {
    int*  cnt  = (int*)d_ws;
    int*  off  = cnt + WS_OFF;
    int*  bsum = cnt + WS_BSUM;
    int2* srt  = (int2*)(cnt + WS_SRT);
    float* degf = (float*)cnt;

    hipMemsetAsync(cnt, 0, (size_t)N_NODES * sizeof(int), stream);
    hist_kernel<<<(N_EDGES + 255) / 256, 256, 0, stream>>>(ei, cnt);
    block_sum_kernel<<<NB_SCAN, 256, 0, stream>>>(cnt, bsum);
    scan_bsum_kernel<<<1, 128, 0, stream>>>(bsum, off);
    scan_offsets_kernel<<<NB_SCAN, 256, 0, stream>>>(cnt, bsum, off);
    hipMemsetAsync(cnt, 0, (size_t)N_NODES * sizeof(int), stream);
    fill_kernel<<<(N_EDGES + 255) / 256, 256, 0, stream>>>(ei, ew, off, cnt, srt);

    if (ws_size >= WS_T2_BYTES) {
      unsigned* xh = (unsigned*)(cnt + WS_XH);
      convert_kernel<<<(N_NODES * D / 8) / 256, 256, 0, stream>>>(x, (uint4*)xh);
      gather_bf16_kernel<<<(N_NODES * 32 + 255) / 256, 256, 0, stream>>>(xh, off, srt, out, degf);
    } else {
      gather_f32_kernel<<<(N_NODES * 32 + 255) / 256, 256, 0, stream>>>(x, off, srt, out, degf);
    }
    fused_gemm_kernel<<<N_NODES / 32, 256, 0, stream>>>(x, Wl, bl, Wa, ba, degf, out);
  } else {
    float* deg = (float*)d_ws;
    hipMemsetAsync(out, 0, (size_t)N_NODES * D * sizeof(float), stream);
    hipMemsetAsync(deg, 0, (size_t)N_NODES * sizeof(float), stream);
    scatter_kernel<<<(N_EDGES * 32) / 256, 256, 0, stream>>>(x, ei, ew, out, deg);
    fused_gemm_kernel<<<N_NODES / 32, 256, 0, stream>>>(x, Wl, bl, Wa, ba, deg, out);
  }
}